// Round 4
// baseline (441.287 us; speedup 1.0000x reference)
//
#include <hip/hip_runtime.h>

#define N_NODES   50000
#define N_EDGES   800000
#define DIM       64
#define NUM_GRAPHS 512
#define EPS       1e-5f

#define SB   1024
#define NSB  ((N_NODES + SB - 1) / SB)   // 49 scan blocks

#define BSH  5                            // 32 nodes per bucket
#define NBK  ((N_NODES + 31) / 32)        // 1563 buckets

// ---------------------------------------------------------------- zero init
__global__ void k_zero(int* __restrict__ deg, float* __restrict__ sums2,
                       float* __restrict__ sums3, float* __restrict__ pooled) {
    int i = blockIdx.x * 256 + threadIdx.x;
    if (i < N_NODES) deg[i] = 0;
    if (i < 128) { sums2[i] = 0.f; sums3[i] = 0.f; }
    if (i < NUM_GRAPHS * DIM) pooled[i] = 0.f;
}

// ---------------------------------------------------------------- degree count
__global__ void k_count(const int* __restrict__ dst, int* __restrict__ deg) {
    int i = blockIdx.x * 256 + threadIdx.x;
    if (i < N_EDGES) atomicAdd(&deg[dst[i]], 1);
}

// ---------------------------------------------------------------- scan phase 1: per-block sums
__global__ void __launch_bounds__(1024)
k_scan1(const int* __restrict__ deg, int* __restrict__ bsum) {
    __shared__ int red[16];
    int t = threadIdx.x;
    int i = blockIdx.x * SB + t;
    int v = (i < N_NODES) ? deg[i] : 0;
#pragma unroll
    for (int d = 32; d; d >>= 1) v += __shfl_down(v, d, 64);
    if ((t & 63) == 0) red[t >> 6] = v;
    __syncthreads();
    if (t < 16) {
        int s = red[t];
#pragma unroll
        for (int d = 8; d; d >>= 1) s += __shfl_down(s, d, 16);
        if (t == 0) bsum[blockIdx.x] = s;
    }
}

// ---------------------------------------------------------------- scan phase 2: scan of 49 block sums (1 wave)
__global__ void k_scan2(const int* __restrict__ bsum, int* __restrict__ boff) {
    int t = threadIdx.x;   // 64 threads
    int v = (t < NSB) ? bsum[t] : 0;
    int orig = v;
#pragma unroll
    for (int d = 1; d < 64; d <<= 1) {
        int u = __shfl_up(v, d, 64);
        if (t >= d) v += u;
    }
    if (t < NSB) boff[t] = v - orig;   // exclusive prefix
}

// ---------------------------------------------------------------- scan phase 3: full exclusive scan, write off/cursor/invd
__global__ void __launch_bounds__(1024)
k_scan3(const int* __restrict__ deg, const int* __restrict__ boff,
        int* __restrict__ off, int* __restrict__ cursor, float* __restrict__ invd) {
    __shared__ int wsum[16];
    int t = threadIdx.x, lane = t & 63, w = t >> 6;
    int i = blockIdx.x * SB + t;
    int d = (i < N_NODES) ? deg[i] : 0;
    int v = d;
#pragma unroll
    for (int s = 1; s < 64; s <<= 1) {
        int u = __shfl_up(v, s, 64);
        if (lane >= s) v += u;
    }
    if (lane == 63) wsum[w] = v;
    __syncthreads();
    if (t < 16) {
        int x = wsum[t];
#pragma unroll
        for (int s = 1; s < 16; s <<= 1) {
            int u = __shfl_up(x, s, 16);
            if (t >= s) x += u;
        }
        wsum[t] = x;   // inclusive across waves (lockstep within wave 0)
    }
    __syncthreads();
    if (i < N_NODES) {
        int ex = boff[blockIdx.x] + ((w > 0) ? wsum[w - 1] : 0) + v - d;
        off[i] = ex;
        cursor[i] = ex;
        invd[i] = 1.0f / (float)max(d, 1);
        if (i == N_NODES - 1) off[N_NODES] = ex + d;
    }
}

// ---------------------------------------------------------------- bucket cursor init: bcur[b] = off[b*32]
__global__ void k_binit(const int* __restrict__ off, int* __restrict__ bcur) {
    int b = blockIdx.x * 256 + threadIdx.x;
    if (b < NBK) bcur[b] = off[b << BSH];
}

// ---------------------------------------------------------------- pass 1: bucket-ordered edge copy (write-local)
__global__ void k_bscatter(const int* __restrict__ src, const int* __restrict__ dst,
                           int* __restrict__ bcur, int* __restrict__ ebs,
                           int* __restrict__ ebd) {
    int i = blockIdx.x * 256 + threadIdx.x;
    if (i < N_EDGES) {
        int d = dst[i];
        int p = atomicAdd(&bcur[d >> BSH], 1);
        ebs[p] = src[i];
        ebd[p] = d;
    }
}

// ---------------------------------------------------------------- pass 2: final CSR scatter (bucket-local stores)
__global__ void k_scatter2(const int* __restrict__ ebs, const int* __restrict__ ebd,
                           int* __restrict__ cursor, int* __restrict__ csr_src) {
    int i = blockIdx.x * 256 + threadIdx.x;
    if (i < N_EDGES) {
        int q = atomicAdd(&cursor[ebd[i]], 1);
        csr_src[q] = ebs[i];
    }
}

// ---------------------------------------------------------------- dual GEMM, weights in registers
// xs = BN(x)@Ws + b ; xn = BN(x)@Wn.   32 rows/block, lane = out column.
#define GR 32   // rows per block
template<bool BN>
__global__ void __launch_bounds__(256, 3)
k_gemm(const float* __restrict__ x, const float* __restrict__ Ws,
       const float* __restrict__ Wn, const float* __restrict__ bias,
       const float* __restrict__ bn_a, const float* __restrict__ bn_c,
       float* __restrict__ xs, float* __restrict__ xn) {
    __shared__ float sX[GR][DIM];
    int tid = threadIdx.x;
    int lane = tid & 63, w = tid >> 6;

    // per-thread column of each weight matrix, fully unrolled -> registers
    float wsr[DIM], wnr[DIM];
#pragma unroll
    for (int k = 0; k < DIM; ++k) {
        wsr[k] = Ws[k * DIM + lane];
        wnr[k] = Wn[k * DIM + lane];
    }
    float bv = bias[lane];
    float aL = 1.f, cL = 0.f;
    if constexpr (BN) { aL = bn_a[lane]; cL = bn_c[lane]; }

    int rowBase = blockIdx.x * GR;
    // stage BN-folded rows (each wave stages rows w, w+4, ..., w+28; coalesced)
#pragma unroll
    for (int r = 0; r < GR / 4; ++r) {
        int row = r * 4 + w;
        int gr = rowBase + row;
        float v = (gr < N_NODES) ? x[gr * DIM + lane] : 0.f;
        sX[row][lane] = fmaf(v, aL, cL);
    }
    __syncthreads();

    // wave w computes rows [w*8, w*8+8)
#pragma unroll
    for (int r = 0; r < 8; ++r) {
        int row = w * 8 + r;
        float s = bv, n = 0.f;
#pragma unroll
        for (int kg = 0; kg < DIM / 4; ++kg) {
            float4 xv = *reinterpret_cast<const float4*>(&sX[row][kg * 4]);
            s = fmaf(xv.x, wsr[kg * 4 + 0], s); n = fmaf(xv.x, wnr[kg * 4 + 0], n);
            s = fmaf(xv.y, wsr[kg * 4 + 1], s); n = fmaf(xv.y, wnr[kg * 4 + 1], n);
            s = fmaf(xv.z, wsr[kg * 4 + 2], s); n = fmaf(xv.z, wnr[kg * 4 + 2], n);
            s = fmaf(xv.w, wsr[kg * 4 + 3], s); n = fmaf(xv.w, wnr[kg * 4 + 3], n);
        }
        int grow = rowBase + row;
        if (grow < N_NODES) {
            xs[grow * DIM + lane] = s;
            xn[grow * DIM + lane] = n;
        }
    }
}

// ---------------------------------------------------------------- aggregate: h = relu(xs + inv_deg * sum_{src} xn[src])
template<bool POOL>
__global__ void __launch_bounds__(256)
k_agg(const float* __restrict__ xs, const float* __restrict__ xn,
      const int* __restrict__ off, const int* __restrict__ csr_src,
      const float* __restrict__ inv_deg, const int* __restrict__ gind,
      float* __restrict__ h, float* __restrict__ pooled) {
    int lane = threadIdx.x & 63, w = threadIdx.x >> 6;
    int row = blockIdx.x * 4 + w;
    if (row >= N_NODES) return;
    int jb = off[row], je = off[row + 1];
    float acc = 0.f;
    int j = jb;
    for (; j + 4 <= je; j += 4) {
        int i0 = csr_src[j], i1 = csr_src[j + 1], i2 = csr_src[j + 2], i3 = csr_src[j + 3];
        float v0 = xn[i0 * DIM + lane];
        float v1 = xn[i1 * DIM + lane];
        float v2 = xn[i2 * DIM + lane];
        float v3 = xn[i3 * DIM + lane];
        acc += (v0 + v1) + (v2 + v3);
    }
    for (; j < je; ++j) acc += xn[csr_src[j] * DIM + lane];
    float val = fmaf(acc, inv_deg[row], xs[row * DIM + lane]);
    val = fmaxf(val, 0.f);
    h[row * DIM + lane] = val;
    if constexpr (POOL) {
        int g = gind[row];
        atomicAdd(&pooled[g * DIM + lane], val);
    }
}

// ---------------------------------------------------------------- BN stats (sum, sumsq per channel)
__global__ void __launch_bounds__(256)
k_stats(const float* __restrict__ h, float* __restrict__ sums) {
    int lane = threadIdx.x & 63, w = threadIdx.x >> 6;
    float s = 0.f, q = 0.f;
    for (int r = blockIdx.x * 4 + w; r < N_NODES; r += gridDim.x * 4) {
        float v = h[r * DIM + lane];
        s += v;
        q = fmaf(v, v, q);
    }
    __shared__ float sS[4][DIM], sQ[4][DIM];
    sS[w][lane] = s; sQ[w][lane] = q;
    __syncthreads();
    if (w == 0) {
        float ts = sS[0][lane] + sS[1][lane] + sS[2][lane] + sS[3][lane];
        float tq = sQ[0][lane] + sQ[1][lane] + sQ[2][lane] + sQ[3][lane];
        atomicAdd(&sums[lane], ts);
        atomicAdd(&sums[DIM + lane], tq);
    }
}

// ---------------------------------------------------------------- BN finalize: a = g*rsqrt(var+eps), c = be - mean*a
__global__ void k_bnfin(const float* __restrict__ sums, const float* __restrict__ g,
                        const float* __restrict__ be, float* __restrict__ a,
                        float* __restrict__ c) {
    int t = threadIdx.x;  // 64 threads
    float m = sums[t] * (1.0f / N_NODES);
    float q = sums[DIM + t] * (1.0f / N_NODES);
    float v = q - m * m;
    float inv = 1.0f / sqrtf(v + EPS);
    float av = g[t] * inv;
    a[t] = av;
    c[t] = be[t] - m * av;
}

// ---------------------------------------------------------------- MLP head (one block per graph)
__global__ void __launch_bounds__(128)
k_mlp(const float* __restrict__ pooled,
      const float* __restrict__ W1, const float* __restrict__ b1,
      const float* __restrict__ W2, const float* __restrict__ b2,
      const float* __restrict__ W3, const float* __restrict__ b3,
      float* __restrict__ out) {
    __shared__ float sp[64], s1[128], s2[64];
    int g = blockIdx.x, t = threadIdx.x;
    if (t < 64) sp[t] = pooled[g * 64 + t];
    __syncthreads();
    {
        float acc = b1[t];
#pragma unroll
        for (int k = 0; k < 64; ++k) acc = fmaf(sp[k], W1[k * 128 + t], acc);
        s1[t] = fmaxf(acc, 0.f);
    }
    __syncthreads();
    if (t < 64) {
        float acc = b2[t];
#pragma unroll
        for (int k = 0; k < 128; ++k) acc = fmaf(s1[k], W2[k * 64 + t], acc);
        s2[t] = fmaxf(acc, 0.f);
    }
    __syncthreads();
    if (t < 10) {
        float acc = b3[t];
#pragma unroll
        for (int k = 0; k < 64; ++k) acc = fmaf(s2[k], W3[k * 10 + t], acc);
        out[g * 10 + t] = acc;
    }
}

// ---------------------------------------------------------------- launch
extern "C" void kernel_launch(void* const* d_in, const int* in_sizes, int n_in,
                              void* d_out, int out_size, void* d_ws, size_t ws_size,
                              hipStream_t stream) {
    const float* x0   = (const float*)d_in[0];
    const int* e_src  = (const int*)d_in[1];
    const int* e_dst  = (const int*)d_in[2];
    const int* gind   = (const int*)d_in[3];
    // d_in[4] = labels (unused)
    const float* Ws1 = (const float*)d_in[5],  *Wn1 = (const float*)d_in[6],  *b1 = (const float*)d_in[7];
    const float* Ws2 = (const float*)d_in[8],  *Wn2 = (const float*)d_in[9],  *b2 = (const float*)d_in[10];
    const float* Ws3 = (const float*)d_in[11], *Wn3 = (const float*)d_in[12], *b3 = (const float*)d_in[13];
    const float* g2  = (const float*)d_in[14], *be2 = (const float*)d_in[15];
    const float* g3  = (const float*)d_in[16], *be3 = (const float*)d_in[17];
    const float* fcW1 = (const float*)d_in[18], *fcb1 = (const float*)d_in[19];
    const float* fcW2 = (const float*)d_in[20], *fcb2 = (const float*)d_in[21];
    const float* fcW3 = (const float*)d_in[22], *fcb3 = (const float*)d_in[23];
    float* out = (float*)d_out;

    char* p = (char*)d_ws;
    auto carve = [&](size_t bytes) { void* r = (void*)p; p += (bytes + 255) & ~(size_t)255; return r; };
    int*   deg     = (int*)  carve(N_NODES * 4);
    int*   off     = (int*)  carve((N_NODES + 1) * 4);
    int*   cursor  = (int*)  carve(N_NODES * 4);
    int*   csr_src = (int*)  carve(N_EDGES * 4);
    float* invd    = (float*)carve(N_NODES * 4);
    int*   bsum    = (int*)  carve(NSB * 4);
    int*   boff    = (int*)  carve((NSB + 1) * 4);
    int*   bcur    = (int*)  carve(NBK * 4);
    float* sums2   = (float*)carve(128 * 4);
    float* sums3   = (float*)carve(128 * 4);
    float* a2      = (float*)carve(64 * 4);
    float* c2      = (float*)carve(64 * 4);
    float* a3      = (float*)carve(64 * 4);
    float* c3      = (float*)carve(64 * 4);
    float* pooled  = (float*)carve(NUM_GRAPHS * DIM * 4);
    float* bufH    = (float*)carve((size_t)N_NODES * DIM * 4);
    float* bufXS   = (float*)carve((size_t)N_NODES * DIM * 4);
    float* bufXN   = (float*)carve((size_t)N_NODES * DIM * 4);

    // bucket-ordered edge scratch aliases the GEMM buffers (used only later)
    int* ebs = (int*)bufXS;
    int* ebd = (int*)bufXN;

    const int EB = (N_EDGES + 255) / 256;           // 3125
    const int GB = (N_NODES + GR - 1) / GR;         // 1563 (gemm: 32 rows/block)
    const int AB = (N_NODES + 3) / 4;               // 12500 (agg: 4 rows/block)

    k_zero<<<(N_NODES + 255) / 256, 256, 0, stream>>>(deg, sums2, sums3, pooled);
    k_count<<<EB, 256, 0, stream>>>(e_dst, deg);
    k_scan1<<<NSB, SB, 0, stream>>>(deg, bsum);
    k_scan2<<<1, 64, 0, stream>>>(bsum, boff);
    k_scan3<<<NSB, SB, 0, stream>>>(deg, boff, off, cursor, invd);
    k_binit<<<(NBK + 255) / 256, 256, 0, stream>>>(off, bcur);
    k_bscatter<<<EB, 256, 0, stream>>>(e_src, e_dst, bcur, ebs, ebd);
    k_scatter2<<<EB, 256, 0, stream>>>(ebs, ebd, cursor, csr_src);

    // Layer 1 (no BN on input)
    k_gemm<false><<<GB, 256, 0, stream>>>(x0, Ws1, Wn1, b1, nullptr, nullptr, bufXS, bufXN);
    k_agg<false><<<AB, 256, 0, stream>>>(bufXS, bufXN, off, csr_src, invd, nullptr, bufH, nullptr);

    // BN2 stats + Layer 2
    k_stats<<<240, 256, 0, stream>>>(bufH, sums2);
    k_bnfin<<<1, 64, 0, stream>>>(sums2, g2, be2, a2, c2);
    k_gemm<true><<<GB, 256, 0, stream>>>(bufH, Ws2, Wn2, b2, a2, c2, bufXS, bufXN);
    k_agg<false><<<AB, 256, 0, stream>>>(bufXS, bufXN, off, csr_src, invd, nullptr, bufH, nullptr);

    // BN3 stats + Layer 3 (fused pooling)
    k_stats<<<240, 256, 0, stream>>>(bufH, sums3);
    k_bnfin<<<1, 64, 0, stream>>>(sums3, g3, be3, a3, c3);
    k_gemm<true><<<GB, 256, 0, stream>>>(bufH, Ws3, Wn3, b3, a3, c3, bufXS, bufXN);
    k_agg<true><<<AB, 256, 0, stream>>>(bufXS, bufXN, off, csr_src, invd, gind, bufH, pooled);

    // MLP head
    k_mlp<<<NUM_GRAPHS, 128, 0, stream>>>(pooled, fcW1, fcb1, fcW2, fcb2, fcW3, fcb3, out);
}